// Round 4
// baseline (146.756 us; speedup 1.0000x reference)
//
#include <hip/hip_runtime.h>
#include <math.h>

// TOF PET forward projection — f32, STRICTLY UNFUSED (numpy semantics).
// Evidence chain: R0 ("unfused" via __fmul_rn/__fadd_rn) and R2 (explicit
// __fmaf_rn) produced bit-identical absmax 0.140625 -> HIP's __f*_rn are plain
// ops and hipcc's default -ffp-contract=fast-honor-pragmas fused both builds.
// f64 (R1) gave 0.125 -> ref is not exact math; it's numpy f32 (never fused).
// Fix: #pragma clang fp contract(off) over the kernel body + numpy's exact op
// order in the index path (t = tmin + frac*span; pts = p1 + t*d;
// (pts+200)/3.125; floor; clip). Comparison is on the bf16 grid, so only
// voxel-index flips matter; weight-path ulp noise (__expf, sum order) is
// invisible.
// One wave (64 lanes) per LOR; lane handles samples {lane, lane+64} of 128.
// TOF window |dev| <= 3*sigma = 90 mm culls ~3/4 of gathers exactly (ref
// weight is identically 0 outside; the window compare uses the same dev).

#define LORS_PER_BLOCK 4

__global__ __launch_bounds__(256) void proj_kernel(
    const float* __restrict__ image,
    const float* __restrict__ lors,
    float* __restrict__ out,
    int n_lors)
{
#pragma clang fp contract(off)
    const int lane = threadIdx.x & 63;
    const int wave = threadIdx.x >> 6;
    const int lor  = blockIdx.x * LORS_PER_BLOCK + wave;
    if (lor >= n_lors) return;

    const float* lp = lors + (size_t)lor * 7;
    const float p1x = lp[0], p1y = lp[1], p1z = lp[2];
    const float p2x = lp[3], p2y = lp[4], p2z = lp[5];
    const float ttof = lp[6];

    const float dx = p2x - p1x;
    const float dy = p2y - p1y;
    const float dz = p2z - p1z;

    // L = ||d||, numpy order: sqrt(((dx*dx) + (dy*dy)) + (dz*dz)), unfused.
    const float L = sqrtf(((dx * dx) + (dy * dy)) + (dz * dz));

    const float eps = 1e-8f;
    const float sdx = (fabsf(dx) < eps) ? eps : dx;
    const float sdy = (fabsf(dy) < eps) ? eps : dy;
    const float sdz = (fabsf(dz) < eps) ? eps : dz;

    // slab intersection with box [-200,200]^3 (IEEE rn division, unfused)
    const float tax = (-200.0f - p1x) / sdx;
    const float tbx = ( 200.0f - p1x) / sdx;
    const float tay = (-200.0f - p1y) / sdy;
    const float tby = ( 200.0f - p1y) / sdy;
    const float taz = (-200.0f - p1z) / sdz;
    const float tbz = ( 200.0f - p1z) / sdz;

    const float tmin = fmaxf(fmaxf(fmaxf(fminf(tax, tbx), fminf(tay, tby)),
                                   fminf(taz, tbz)), 0.0f);
    const float tmax = fminf(fminf(fminf(fmaxf(tax, tbx), fmaxf(tay, tby)),
                                   fmaxf(taz, tbz)), 1.0f);
    const float span = fmaxf(tmax - tmin, 0.0f);

    if (!(tmax > tmin)) {          // valid == (tmax > tmin); ref proj == 0
        if (lane == 0) out[lor] = 0.0f;
        return;
    }

    float acc = 0.0f;

#pragma unroll
    for (int k = 0; k < 2; ++k) {
        const int j = lane + (k << 6);
        // frac = (j + 0.5)/128 — exact (power-of-2 divide)
        const float frac = ((float)j + 0.5f) / 128.0f;
        // t = tmin + frac*span  — UNFUSED (numpy)
        const float t = tmin + (frac * span);
        // s = (t - 0.5)*L ; dev = s - ttof — unfused (window only; coarse)
        const float dev = ((t - 0.5f) * L) - ttof;

        if (fabsf(dev) <= 90.0f) {   // 3*sigma TOF window; outside -> w == 0
            // pts = p1 + t*d — UNFUSED (numpy)
            const float px = p1x + (t * dx);
            const float py = p1y + (t * dy);
            const float pz = p1z + (t * dz);
            // vox = clip(floor((pts - (-200))/3.125), 0, 127); IEEE rn div
            int vx = (int)floorf((px + 200.0f) / 3.125f);
            int vy = (int)floorf((py + 200.0f) / 3.125f);
            int vz = (int)floorf((pz + 200.0f) / 3.125f);
            vx = min(max(vx, 0), 127);
            vy = min(max(vy, 0), 127);
            vz = min(max(vz, 0), 127);

            const float val = image[(((vx << 7) | vy) << 7) | vz];

            // w = 5/sqrt(2*pi*900) * exp(-0.5*dev^2/900); ulp noise invisible
            const float w = 0.06649038f *
                            __expf(((-0.5f * dev) * dev) / 900.0f);
            acc += val * w;
        }
    }

    // wave butterfly reduction over 64 lanes
#pragma unroll
    for (int off = 32; off > 0; off >>= 1)
        acc += __shfl_xor(acc, off, 64);

    if (lane == 0) {
        const float step = (span * L) / 128.0f;
        out[lor] = acc * step;
    }
}

extern "C" void kernel_launch(void* const* d_in, const int* in_sizes, int n_in,
                              void* d_out, int out_size, void* d_ws, size_t ws_size,
                              hipStream_t stream) {
    const float* image = (const float*)d_in[0];   // 128^3 fp32
    const float* lors  = (const float*)d_in[1];   // N x 7 fp32
    float* out = (float*)d_out;                   // N fp32
    const int n_lors = in_sizes[1] / 7;
    const int blocks = (n_lors + LORS_PER_BLOCK - 1) / LORS_PER_BLOCK;
    proj_kernel<<<blocks, 256, 0, stream>>>(image, lors, out, n_lors);
}